// Round 15
// baseline (125.561 us; speedup 1.0000x reference)
//
#include <hip/hip_runtime.h>
#include <hip/hip_bf16.h>

// Problem: B=2, S=2048, D=1024, H=16, HD=64
// out = (rg*softmax(QK^T/8,causal) + sg*I - cg*tril/rownum) @ V, then @cproj_w

typedef __hip_bfloat16 bf16;
typedef short s16x8 __attribute__((ext_vector_type(8)));
typedef short s16x4 __attribute__((ext_vector_type(4)));
typedef float f32x4 __attribute__((ext_vector_type(4)));

#define NB 2
#define NS 2048
#define ND 1024
#define NH 16
#define NHD 64
// 0.125 * log2(e): folded into q so softmax can use exp2
#define QSCALE 0.18033688011112042f
// 16B-slot XOR swizzle for 128B-row LDS tiles
#define SW(r) (((r) & 7) << 4)

__device__ __forceinline__ float b2f(unsigned short u) {
  union { float f; unsigned int i; } c; c.i = ((unsigned int)u) << 16; return c.f;
}

__device__ __forceinline__ unsigned short f2bu(float f) {
  bf16 t = __float2bfloat16(f);
  unsigned short u;
  __builtin_memcpy(&u, &t, 2);
  return u;
}

// async global->LDS, 16B per lane; LDS dest semantics: wave-uniform base + lane*16
__device__ __forceinline__ void gload_lds16(const void* g, void* l) {
  __builtin_amdgcn_global_load_lds((const __attribute__((address_space(1))) void*)g,
                                   (__attribute__((address_space(3))) void*)l, 16, 0, 0);
}

// ---------------- fused prologue ----------------
// z=0: x f32 -> bf16 (8 floats/thread); z=1..3: weight transpose+convert
__global__ __launch_bounds__(256) void prologue(const float* __restrict__ x,
                                                const float* __restrict__ qk_w,
                                                const float* __restrict__ v_w,
                                                const float* __restrict__ cp_w,
                                                bf16* __restrict__ xb,
                                                bf16* __restrict__ qkwt,
                                                bf16* __restrict__ vwt,
                                                bf16* __restrict__ cpwt) {
  const int z = blockIdx.z;
  const int tx = threadIdx.x, ty = threadIdx.y;  // block (32,8)
  if (z == 0) {
    const int lb = (int)blockIdx.x + 64 * (int)blockIdx.y;   // 0..2047
    const int base = lb * 2048 + (ty * 32 + tx) * 8;
    float4 v0 = *(const float4*)(x + base);
    float4 v1 = *(const float4*)(x + base + 4);
    ushort4 o0, o1;
    o0.x = f2bu(v0.x); o0.y = f2bu(v0.y); o0.z = f2bu(v0.z); o0.w = f2bu(v0.w);
    o1.x = f2bu(v1.x); o1.y = f2bu(v1.y); o1.z = f2bu(v1.z); o1.w = f2bu(v1.w);
    *(ushort4*)(xb + base) = o0;
    *(ushort4*)(xb + base + 4) = o1;
    return;
  }
  const int N = (z == 1) ? 2048 : 1024;
  if ((int)blockIdx.x * 32 >= N) return;
  const float* in = (z == 1) ? qk_w : (z == 2) ? v_w : cp_w;
  bf16* out = (z == 1) ? qkwt : (z == 2) ? vwt : cpwt;
  const int K = 1024;
  __shared__ float tile[32][33];
  int nt = blockIdx.x * 32, kt = blockIdx.y * 32;
#pragma unroll
  for (int j = 0; j < 32; j += 8)
    tile[ty + j][tx] = in[(size_t)(kt + ty + j) * N + nt + tx];
  __syncthreads();
#pragma unroll
  for (int j = 0; j < 32; j += 8)
    out[(size_t)(nt + ty + j) * K + kt + tx] = __float2bfloat16(tile[tx][ty + j]);
}

// ---------------- fused QKV GEMM: 128x128x32, grid (24, 32) = 768 blocks ----------------
// T3 minimum-2-phase: double-buffered LDS, prefetch STAGE(next) issued BEFORE
// computing current tile, ONE barrier per K-step. Load latency hides under MFMA.
__global__ __launch_bounds__(256) void gemm_qkv(const bf16* __restrict__ A,
                                                const bf16* __restrict__ BtQK,
                                                const bf16* __restrict__ BtV,
                                                const float* __restrict__ bias,
                                                bf16* __restrict__ qo, bf16* __restrict__ ko,
                                                bf16* __restrict__ vo) {
  __shared__ alignas(16) bf16 As[2][128 * 32];
  __shared__ alignas(16) bf16 Bs[2][128 * 32];
  const int K = 1024;
  const int tid = threadIdx.x;
  const int wave = tid >> 6, lane = tid & 63;
  const int l15 = lane & 15, lg = lane >> 4;
  const int wr = wave >> 1, wc = wave & 1;
  const int brow = blockIdx.y * 128, bcol = blockIdx.x * 128;
  const bf16* Bsrc = (bcol < 2048) ? (BtQK + (size_t)bcol * K)
                                   : (BtV + (size_t)(bcol - 2048) * K);

  f32x4 acc[4][4] = {};
  const int r0 = tid >> 2;          // 0..63
  const int kc = (tid & 3) * 8;     // element offset 0,8,16,24
  const bf16* Ag0 = A + (size_t)(brow + r0) * K + kc;
  const bf16* Ag1 = A + (size_t)(brow + r0 + 64) * K + kc;
  const bf16* Bg0 = Bsrc + (size_t)r0 * K + kc;
  const bf16* Bg1 = Bsrc + (size_t)(r0 + 64) * K + kc;

  // prologue: stage k0=0 into buffer 0
  gload_lds16(Ag0, (char*)As[0] + tid * 16);
  gload_lds16(Ag1, (char*)As[0] + 4096 + tid * 16);
  gload_lds16(Bg0, (char*)Bs[0] + tid * 16);
  gload_lds16(Bg1, (char*)Bs[0] + 4096 + tid * 16);
  __syncthreads();

  const bf16* Ar = As[0];
  const bf16* Br = Bs[0];
  char* Aw = (char*)As[1];
  char* Bw = (char*)Bs[1];

  for (int k0 = 0; k0 < K; k0 += 32) {
    // prefetch next K-tile into the other buffer (in flight during MFMA)
    if (k0 + 32 < K) {
      gload_lds16(Ag0 + k0 + 32, Aw + tid * 16);
      gload_lds16(Ag1 + k0 + 32, Aw + 4096 + tid * 16);
      gload_lds16(Bg0 + k0 + 32, Bw + tid * 16);
      gload_lds16(Bg1 + k0 + 32, Bw + 4096 + tid * 16);
    }
    s16x8 af[4], bfr[4];
#pragma unroll
    for (int mi = 0; mi < 4; ++mi)
      af[mi] = *(const s16x8*)(Ar + (wr * 64 + mi * 16 + l15) * 32 + lg * 8);
#pragma unroll
    for (int ni = 0; ni < 4; ++ni)
      bfr[ni] = *(const s16x8*)(Br + (wc * 64 + ni * 16 + l15) * 32 + lg * 8);
#pragma unroll
    for (int mi = 0; mi < 4; ++mi)
#pragma unroll
      for (int ni = 0; ni < 4; ++ni)
        acc[mi][ni] = __builtin_amdgcn_mfma_f32_16x16x32_bf16(af[mi], bfr[ni], acc[mi][ni], 0, 0, 0);
    __syncthreads();                 // publishes prefetch, closes read window
    const bf16* tA = Ar; Ar = (const bf16*)Aw; Aw = (char*)tA;
    const bf16* tB = Br; Br = (const bf16*)Bw; Bw = (char*)tB;
  }

#pragma unroll
  for (int mi = 0; mi < 4; ++mi)
#pragma unroll
    for (int ni = 0; ni < 4; ++ni)
#pragma unroll
      for (int r = 0; r < 4; ++r) {
        int row = brow + wr * 64 + mi * 16 + lg * 4 + r;   // C/D: row=(lane>>4)*4+reg
        int col = bcol + wc * 64 + ni * 16 + l15;          //      col=lane&15
        float v = acc[mi][ni][r];
        int b = row >> 11, s = row & 2047;
        int cc = col & 1023;
        int h = cc >> 6, e = cc & 63;
        if (col < 1024) {
          v = (v + bias[col]) * QSCALE;
          qo[((((size_t)b * NH + h) * NS) + s) * NHD + e] = __float2bfloat16(v);
        } else if (col < 2048) {
          v += bias[col];
          ko[((((size_t)b * NH + h) * NS) + s) * NHD + e] = __float2bfloat16(v);
        } else {
          vo[((((size_t)b * NH + h) * NHD) + e) * NS + s] = __float2bfloat16(v);
        }
      }
}

// ---------------- output GEMM: 128x64x32, grid (16, 32) = 512 blocks ----------------
// Same T3 minimum-2-phase prefetch structure.
__global__ __launch_bounds__(256) void gemm_out(const bf16* __restrict__ A,
                                                const bf16* __restrict__ Bt,
                                                float* __restrict__ of) {
  __shared__ alignas(16) bf16 As[2][128 * 32];
  __shared__ alignas(16) bf16 Bs[2][64 * 32];
  const int K = 1024, N = 1024;
  const int tid = threadIdx.x;
  const int wave = tid >> 6, lane = tid & 63;
  const int l15 = lane & 15, lg = lane >> 4;
  const int brow = blockIdx.y * 128, bcol = blockIdx.x * 64;

  f32x4 acc[2][4] = {};
  const int r0 = tid >> 2;          // 0..63
  const int kc = (tid & 3) * 8;
  const bf16* Ag0 = A + (size_t)(brow + r0) * K + kc;
  const bf16* Ag1 = A + (size_t)(brow + r0 + 64) * K + kc;
  const bf16* Bg0 = Bt + (size_t)(bcol + r0) * K + kc;

  gload_lds16(Ag0, (char*)As[0] + tid * 16);
  gload_lds16(Ag1, (char*)As[0] + 4096 + tid * 16);
  gload_lds16(Bg0, (char*)Bs[0] + tid * 16);
  __syncthreads();

  const bf16* Ar = As[0];
  const bf16* Br = Bs[0];
  char* Aw = (char*)As[1];
  char* Bw = (char*)Bs[1];

  for (int k0 = 0; k0 < K; k0 += 32) {
    if (k0 + 32 < K) {
      gload_lds16(Ag0 + k0 + 32, Aw + tid * 16);
      gload_lds16(Ag1 + k0 + 32, Aw + 4096 + tid * 16);
      gload_lds16(Bg0 + k0 + 32, Bw + tid * 16);
    }
    s16x8 af[2], bfr[4];
#pragma unroll
    for (int mi = 0; mi < 2; ++mi)
      af[mi] = *(const s16x8*)(Ar + (wave * 32 + mi * 16 + l15) * 32 + lg * 8);
#pragma unroll
    for (int ni = 0; ni < 4; ++ni)
      bfr[ni] = *(const s16x8*)(Br + (ni * 16 + l15) * 32 + lg * 8);
#pragma unroll
    for (int mi = 0; mi < 2; ++mi)
#pragma unroll
      for (int ni = 0; ni < 4; ++ni)
        acc[mi][ni] = __builtin_amdgcn_mfma_f32_16x16x32_bf16(af[mi], bfr[ni], acc[mi][ni], 0, 0, 0);
    __syncthreads();
    const bf16* tA = Ar; Ar = (const bf16*)Aw; Aw = (char*)tA;
    const bf16* tB = Br; Br = (const bf16*)Bw; Bw = (char*)tB;
  }

#pragma unroll
  for (int mi = 0; mi < 2; ++mi)
#pragma unroll
    for (int ni = 0; ni < 4; ++ni)
#pragma unroll
      for (int r = 0; r < 4; ++r) {
        int row = brow + wave * 32 + mi * 16 + lg * 4 + r;
        int col = bcol + ni * 16 + l15;
        of[(size_t)row * N + col] = acc[mi][ni][r];
      }
}

// ---------------- fused causal shaped attention: 8-wave paired blocks ----------------
// grid (32=hb, 16=j), 512 threads. Waves 0-3: qt=j, waves 4-7: qt=31-j.
// No-max softmax (scores ~N(0,0.6) in log2 domain; exp2(-inf)=0 keeps causality).
// Row sum on the matrix pipe: acc_l += mfma(P, ones). Prefix-V via ones/masked
// MFMA every tile (R9/R10 proven-good form).
__global__ __launch_bounds__(512, 4) void attn_kernel(const bf16* __restrict__ qb,
                                                      const bf16* __restrict__ kb,
                                                      const bf16* __restrict__ vtb,
                                                      const float* __restrict__ rg,
                                                      const float* __restrict__ sg,
                                                      const float* __restrict__ cg,
                                                      bf16* __restrict__ out) {
  const int hb = blockIdx.x;            // h + 16*b
  const int h = hb & 15, b = hb >> 4;
  const int j = blockIdx.y;             // 0..15
  const int tid = threadIdx.x, wave = tid >> 6, lane = tid & 63;
  const int l15 = lane & 15, lg = lane >> 4;
  const int grp = wave >> 2, wv4 = wave & 3;
  const int qt = grp ? (31 - j) : j;    // this wave's q-tile
  const int ntm1 = 31 - j;              // last kv-tile index staged by the block

  __shared__ alignas(16) char Ks[2][64 * 128];  // K tile [kv][hd], swizzled, dbuf
  __shared__ alignas(16) char Vs[2][64 * 128];  // V^T tile [hd][kv], swizzled, dbuf
  __shared__ alignas(16) char Pl[8][2048];      // per-wave P [16 q][64 k], swizzled
  char* Plw = Pl[wave];
  const int swz = ((((l15 >> 3) ^ l15) & 7) << 4);

  const size_t hoff = ((size_t)b * NH + h) * NS * NHD;
  const bf16* K = kb + hoff;
  const bf16* VT = vtb + hoff;               // [HD=64][S=2048]
  const float rgh = rg[h], sgh = sg[h], cgh = cg[h];

  const int qbase = qt * 64 + wv4 * 16;
  const int qloc = wv4 * 16 + l15;           // q row within 64-tile for this lane

  // Q fragments (B-operand): Q[q=l15][hd]
  const bf16* Q = qb + hoff;
  s16x8 qa0 = *(const s16x8*)(Q + (size_t)(qbase + l15) * NHD + lg * 8);
  s16x8 qa1 = *(const s16x8*)(Q + (size_t)(qbase + l15) * NHD + 32 + lg * 8);

  // loop-invariant causal fragments for the prefix-sum MFMA (diag tile)
  const short ONE = 0x3F80;
  const s16x8 ones = {ONE, ONE, ONE, ONE, ONE, ONE, ONE, ONE};
  s16x8 pc0, pc1;
#pragma unroll
  for (int jj = 0; jj < 8; ++jj) {
    pc0[jj] = (lg * 8 + jj <= qloc) ? ONE : (short)0;
    pc1[jj] = (32 + lg * 8 + jj <= qloc) ? ONE : (short)0;
  }

  f32x4 acc_o[4] = {};
  f32x4 acc_c[4] = {};
  f32x4 acc_l = {};                    // row-sum of P (all cols identical)

  // staging: 512 threads, one 16B chunk of K and one of V per thread per tile
  const int srow = tid >> 3;           // 0..63
  const int sce = (tid & 7) * 8;       // element offset within row
  const int scb = (sce * 2) ^ SW(srow);

  // preload tile 0 into registers
  s16x8 kra = *(const s16x8*)(K + (size_t)srow * NHD + sce);
  s16x8 vra = *(const s16x8*)(VT + (size_t)srow * NS + sce);

  for (int t = 0; t <= ntm1; ++t) {
    char* Kb = Ks[t & 1];
    char* Vb = Vs[t & 1];
    // stage tile t (regs loaded last iter); other waves may still compute t-1
    *(s16x8*)(Kb + srow * 128 + scb) = kra;
    *(s16x8*)(Vb + srow * 128 + scb) = vra;
    if (t < ntm1) {                    // prefetch next tile (hides under compute)
      kra = *(const s16x8*)(K + ((size_t)(t + 1) * 64 + srow) * NHD + sce);
      vra = *(const s16x8*)(VT + (size_t)srow * NS + (t + 1) * 64 + sce);
    }
    __syncthreads();                   // tile t staged by all waves

    if (t > qt) continue;              // group done after its diag (barrier-only)
    const bool diag = (t == qt);

    // ---- swapped QK^T: sc[c] = S^T[k = c*16 + lg*4 + r][q = l15] ----
    f32x4 sc[4] = {};
    __builtin_amdgcn_s_setprio(1);
#pragma unroll
    for (int c = 0; c < 4; ++c) {
      const int R = c * 16 + l15;
      s16x8 kf0 = *(const s16x8*)(Kb + R * 128 + ((lg * 16) ^ SW(R)));
      s16x8 kf1 = *(const s16x8*)(Kb + R * 128 + ((64 + lg * 16) ^ SW(R)));
      sc[c] = __builtin_amdgcn_mfma_f32_16x16x32_bf16(kf0, qa0, sc[c], 0, 0, 0);
      sc[c] = __builtin_amdgcn_mfma_f32_16x16x32_bf16(kf1, qa1, sc[c], 0, 0, 0);
    }
    __builtin_amdgcn_s_setprio(0);

    // causal mask on the diagonal tile
    if (diag) {
#pragma unroll
      for (int c = 0; c < 4; ++c)
#pragma unroll
        for (int r = 0; r < 4; ++r)
          if (c * 16 + lg * 4 + r > qloc) sc[c][r] = -INFINITY;
    }

    // p = exp2(s) directly (no max subtraction); pack into A-frag layout:
    // row q=l15, k = c*16 + lg*4 + r
#pragma unroll
    for (int c = 0; c < 4; ++c) {
      s16x4 pk;
      pk[0] = (short)f2bu(exp2f(sc[c][0]));
      pk[1] = (short)f2bu(exp2f(sc[c][1]));
      pk[2] = (short)f2bu(exp2f(sc[c][2]));
      pk[3] = (short)f2bu(exp2f(sc[c][3]));
      *(s16x4*)(Plw + l15 * 128 + ((c * 32 + lg * 8) ^ swz)) = pk;
    }
    // read back as A-frags: P[q=l15][kv = khalf*32 + lg*8 + jj]
    s16x8 pa0 = *(const s16x8*)(Plw + l15 * 128 + ((lg * 16) ^ swz));
    s16x8 pa1 = *(const s16x8*)(Plw + l15 * 128 + ((64 + lg * 16) ^ swz));

    const s16x8 qc0 = diag ? pc0 : ones;
    const s16x8 qc1 = diag ? pc1 : ones;

    // ---- PV + prefix-V + row-sum, all on the matrix pipe ----
    __builtin_amdgcn_s_setprio(1);
    acc_l = __builtin_amdgcn_mfma_f32_16x16x32_bf16(pa0, ones, acc_l, 0, 0, 0);
    acc_l = __builtin_amdgcn_mfma_f32_16x16x32_bf16(pa1, ones, acc_l, 0, 0, 0);
#pragma unroll
    for (int sub = 0; sub < 4; ++sub) {
      const int Rv = sub * 16 + l15;
      s16x8 vf0 = *(const s16x8*)(Vb + Rv * 128 + ((lg * 16) ^ SW(Rv)));
      s16x8 vf1 = *(const s16x8*)(Vb + Rv * 128 + ((64 + lg * 16) ^ SW(Rv)));
      acc_o[sub] = __builtin_amdgcn_mfma_f32_16x16x32_bf16(pa0, vf0, acc_o[sub], 0, 0, 0);
      acc_o[sub] = __builtin_amdgcn_mfma_f32_16x16x32_bf16(pa1, vf1, acc_o[sub], 0, 0, 0);
      acc_c[sub] = __builtin_amdgcn_mfma_f32_16x16x32_bf16(qc0, vf0, acc_c[sub], 0, 0, 0);
      acc_c[sub] = __builtin_amdgcn_mfma_f32_16x16x32_bf16(qc1, vf1, acc_c[sub], 0, 0, 0);
    }
    __builtin_amdgcn_s_setprio(0);

    // ---- epilogue at this group's diagonal tile (V tile still resident) ----
    if (diag) {
      float linv[4];
#pragma unroll
      for (int r = 0; r < 4; ++r) linv[r] = 1.0f / acc_l[r];
#pragma unroll
      for (int sub = 0; sub < 4; ++sub) {
        const int d = sub * 16 + l15;
        const int cb = wv4 * 32 + lg * 8;  // byte col of local q rows (8B aligned)
        s16x4 vr4 = *(const s16x4*)(Vb + d * 128 + (cb ^ SW(d)));
        unsigned short vbits[4];
        __builtin_memcpy(vbits, &vr4, 8);
#pragma unroll
        for (int r = 0; r < 4; ++r) {
          int q = qbase + lg * 4 + r;
          float val = rgh * acc_o[sub][r] * linv[r] + sgh * b2f(vbits[r]) -
                      cgh * acc_c[sub][r] / (float)(q + 1);
          out[((size_t)b * NS + q) * ND + h * NHD + d] = __float2bfloat16(val);
        }
      }
    }
  }
}

extern "C" void kernel_launch(void* const* d_in, const int* in_sizes, int n_in,
                              void* d_out, int out_size, void* d_ws, size_t ws_size,
                              hipStream_t stream) {
  const float* x = (const float*)d_in[0];
  const float* qk_w = (const float*)d_in[1];
  const float* qk_b = (const float*)d_in[2];
  const float* v_w = (const float*)d_in[3];
  const float* cproj_w = (const float*)d_in[4];
  const float* rg = (const float*)d_in[5];
  const float* sg = (const float*)d_in[6];
  const float* cg = (const float*)d_in[7];
  float* out = (float*)d_out;

  char* p = (char*)d_ws;
  bf16* xb = (bf16*)p;   p += (size_t)4096 * 1024 * 2;   // x bf16 [B*S, D]
  bf16* qkwt = (bf16*)p; p += (size_t)2048 * 1024 * 2;   // qk_w^T bf16 [2D, D]
  bf16* vwt = (bf16*)p;  p += (size_t)1024 * 1024 * 2;   // v_w^T
  bf16* cpwt = (bf16*)p; p += (size_t)1024 * 1024 * 2;   // cproj_w^T
  bf16* qbuf = (bf16*)p; p += (size_t)NB * NH * NS * NHD * 2;
  bf16* kbuf = (bf16*)p; p += (size_t)NB * NH * NS * NHD * 2;
  bf16* vtbuf = (bf16*)p; p += (size_t)NB * NH * NS * NHD * 2;  // V^T [B,H,HD,S]
  bf16* aout = (bf16*)p; p += (size_t)4096 * 1024 * 2;   // attn out [B,S,D]

  prologue<<<dim3(64, 32, 4), dim3(32, 8), 0, stream>>>(x, qk_w, v_w, cproj_w,
                                                        xb, qkwt, vwt, cpwt);
  gemm_qkv<<<dim3(24, 32), 256, 0, stream>>>(xb, qkwt, vwt, qk_b, qbuf, kbuf, vtbuf);
  attn_kernel<<<dim3(32, 16), 512, 0, stream>>>(qbuf, kbuf, vtbuf, rg, sg, cg, aout);
  gemm_out<<<dim3(16, 32), 256, 0, stream>>>(aout, cpwt, out);
}

// Round 16
// 118.707 us; speedup vs baseline: 1.0577x; 1.0577x over previous
//
#include <hip/hip_runtime.h>
#include <hip/hip_bf16.h>

// Problem: B=2, S=2048, D=1024, H=16, HD=64
// out = (rg*softmax(QK^T/8,causal) + sg*I - cg*tril/rownum) @ V, then @cproj_w

typedef __hip_bfloat16 bf16;
typedef short s16x8 __attribute__((ext_vector_type(8)));
typedef short s16x4 __attribute__((ext_vector_type(4)));
typedef float f32x4 __attribute__((ext_vector_type(4)));

#define NB 2
#define NS 2048
#define ND 1024
#define NH 16
#define NHD 64
// 0.125 * log2(e): folded into q so softmax can use exp2
#define QSCALE 0.18033688011112042f
// 16B-slot XOR swizzle for 128B-row LDS tiles
#define SW(r) (((r) & 7) << 4)

__device__ __forceinline__ float b2f(unsigned short u) {
  union { float f; unsigned int i; } c; c.i = ((unsigned int)u) << 16; return c.f;
}

__device__ __forceinline__ unsigned short f2bu(float f) {
  bf16 t = __float2bfloat16(f);
  unsigned short u;
  __builtin_memcpy(&u, &t, 2);
  return u;
}

// async global->LDS, 16B per lane; LDS dest semantics: wave-uniform base + lane*16
__device__ __forceinline__ void gload_lds16(const void* g, void* l) {
  __builtin_amdgcn_global_load_lds((const __attribute__((address_space(1))) void*)g,
                                   (__attribute__((address_space(3))) void*)l, 16, 0, 0);
}

// ---------------- fused prologue ----------------
// z=0: x f32 -> bf16 (8 floats/thread); z=1..3: weight transpose+convert
__global__ __launch_bounds__(256) void prologue(const float* __restrict__ x,
                                                const float* __restrict__ qk_w,
                                                const float* __restrict__ v_w,
                                                const float* __restrict__ cp_w,
                                                bf16* __restrict__ xb,
                                                bf16* __restrict__ qkwt,
                                                bf16* __restrict__ vwt,
                                                bf16* __restrict__ cpwt) {
  const int z = blockIdx.z;
  const int tx = threadIdx.x, ty = threadIdx.y;  // block (32,8)
  if (z == 0) {
    const int lb = (int)blockIdx.x + 64 * (int)blockIdx.y;   // 0..2047
    const int base = lb * 2048 + (ty * 32 + tx) * 8;
    float4 v0 = *(const float4*)(x + base);
    float4 v1 = *(const float4*)(x + base + 4);
    ushort4 o0, o1;
    o0.x = f2bu(v0.x); o0.y = f2bu(v0.y); o0.z = f2bu(v0.z); o0.w = f2bu(v0.w);
    o1.x = f2bu(v1.x); o1.y = f2bu(v1.y); o1.z = f2bu(v1.z); o1.w = f2bu(v1.w);
    *(ushort4*)(xb + base) = o0;
    *(ushort4*)(xb + base + 4) = o1;
    return;
  }
  const int N = (z == 1) ? 2048 : 1024;
  if ((int)blockIdx.x * 32 >= N) return;
  const float* in = (z == 1) ? qk_w : (z == 2) ? v_w : cp_w;
  bf16* out = (z == 1) ? qkwt : (z == 2) ? vwt : cpwt;
  const int K = 1024;
  __shared__ float tile[32][33];
  int nt = blockIdx.x * 32, kt = blockIdx.y * 32;
#pragma unroll
  for (int j = 0; j < 32; j += 8)
    tile[ty + j][tx] = in[(size_t)(kt + ty + j) * N + nt + tx];
  __syncthreads();
#pragma unroll
  for (int j = 0; j < 32; j += 8)
    out[(size_t)(nt + ty + j) * K + kt + tx] = __float2bfloat16(tile[tx][ty + j]);
}

// ---------------- fused QKV GEMM: 128x128x32, grid (24, 32) = 768 blocks ----------------
// R8 form (BK=32, linear LDS, gload_lds w16) + T1 bijective XCD swizzle:
// each XCD gets a contiguous band of 4 row-panels x 24 col-panels -> A-panel
// reused 24x within one XCD L2 (was spread across 8 XCDs).
__global__ __launch_bounds__(256) void gemm_qkv(const bf16* __restrict__ A,
                                                const bf16* __restrict__ BtQK,
                                                const bf16* __restrict__ BtV,
                                                const float* __restrict__ bias,
                                                bf16* __restrict__ qo, bf16* __restrict__ ko,
                                                bf16* __restrict__ vo) {
  __shared__ alignas(16) bf16 As[128 * 32];
  __shared__ alignas(16) bf16 Bs[128 * 32];
  const int K = 1024;
  const int tid = threadIdx.x;
  const int wave = tid >> 6, lane = tid & 63;
  const int l15 = lane & 15, lg = lane >> 4;
  const int wr = wave >> 1, wc = wave & 1;
  // dispatch id (x fastest) -> XCD-contiguous remap (768 = 8 * 96, bijective)
  const int bid = (int)blockIdx.x + (int)blockIdx.y * 24;
  const int sbid = (bid & 7) * 96 + (bid >> 3);
  const int brow = (sbid / 24) * 128, bcol = (sbid % 24) * 128;
  const bf16* Bsrc = (bcol < 2048) ? (BtQK + (size_t)bcol * K)
                                   : (BtV + (size_t)(bcol - 2048) * K);

  f32x4 acc[4][4] = {};
  const int r0 = tid >> 2;          // 0..63
  const int kc = (tid & 3) * 8;     // element offset 0,8,16,24
  char* AsB = (char*)As;
  char* BsB = (char*)Bs;

  for (int k0 = 0; k0 < K; k0 += 32) {
    gload_lds16(A + (size_t)(brow + r0) * K + k0 + kc, AsB + tid * 16);
    gload_lds16(A + (size_t)(brow + r0 + 64) * K + k0 + kc, AsB + 4096 + tid * 16);
    gload_lds16(Bsrc + (size_t)r0 * K + k0 + kc, BsB + tid * 16);
    gload_lds16(Bsrc + (size_t)(r0 + 64) * K + k0 + kc, BsB + 4096 + tid * 16);
    __syncthreads();
    s16x8 af[4], bfr[4];
#pragma unroll
    for (int mi = 0; mi < 4; ++mi)
      af[mi] = *(const s16x8*)(As + (wr * 64 + mi * 16 + l15) * 32 + lg * 8);
#pragma unroll
    for (int ni = 0; ni < 4; ++ni)
      bfr[ni] = *(const s16x8*)(Bs + (wc * 64 + ni * 16 + l15) * 32 + lg * 8);
#pragma unroll
    for (int mi = 0; mi < 4; ++mi)
#pragma unroll
      for (int ni = 0; ni < 4; ++ni)
        acc[mi][ni] = __builtin_amdgcn_mfma_f32_16x16x32_bf16(af[mi], bfr[ni], acc[mi][ni], 0, 0, 0);
    __syncthreads();
  }

#pragma unroll
  for (int mi = 0; mi < 4; ++mi)
#pragma unroll
    for (int ni = 0; ni < 4; ++ni)
#pragma unroll
      for (int r = 0; r < 4; ++r) {
        int row = brow + wr * 64 + mi * 16 + lg * 4 + r;   // C/D: row=(lane>>4)*4+reg
        int col = bcol + wc * 64 + ni * 16 + l15;          //      col=lane&15
        float v = acc[mi][ni][r];
        int b = row >> 11, s = row & 2047;
        int cc = col & 1023;
        int h = cc >> 6, e = cc & 63;
        if (col < 1024) {
          v = (v + bias[col]) * QSCALE;
          qo[((((size_t)b * NH + h) * NS) + s) * NHD + e] = __float2bfloat16(v);
        } else if (col < 2048) {
          v += bias[col];
          ko[((((size_t)b * NH + h) * NS) + s) * NHD + e] = __float2bfloat16(v);
        } else {
          vo[((((size_t)b * NH + h) * NHD) + e) * NS + s] = __float2bfloat16(v);
        }
      }
}

// ---------------- output GEMM: 128x64x32, grid (16, 32) = 512 blocks ----------------
// R14 form + T1 bijective XCD swizzle (512 = 8 * 64 -> 4 row-panels x 16 cols per XCD).
__global__ __launch_bounds__(256) void gemm_out(const bf16* __restrict__ A,
                                                const bf16* __restrict__ Bt,
                                                float* __restrict__ of) {
  __shared__ alignas(16) bf16 As[128 * 32];
  __shared__ alignas(16) bf16 Bs[64 * 32];
  const int K = 1024, N = 1024;
  const int tid = threadIdx.x;
  const int wave = tid >> 6, lane = tid & 63;
  const int l15 = lane & 15, lg = lane >> 4;
  const int bid = (int)blockIdx.x + (int)blockIdx.y * 16;
  const int sbid = (bid & 7) * 64 + (bid >> 3);
  const int brow = (sbid / 16) * 128, bcol = (sbid % 16) * 64;

  f32x4 acc[2][4] = {};
  const int r0 = tid >> 2;          // 0..63
  const int kc = (tid & 3) * 8;
  char* AsB = (char*)As;
  char* BsB = (char*)Bs;

  for (int k0 = 0; k0 < K; k0 += 32) {
    gload_lds16(A + (size_t)(brow + r0) * K + k0 + kc, AsB + tid * 16);
    gload_lds16(A + (size_t)(brow + r0 + 64) * K + k0 + kc, AsB + 4096 + tid * 16);
    gload_lds16(Bt + (size_t)(bcol + r0) * K + k0 + kc, BsB + tid * 16);
    __syncthreads();
    s16x8 af[2], bfr[4];
#pragma unroll
    for (int mi = 0; mi < 2; ++mi)
      af[mi] = *(const s16x8*)(As + (wave * 32 + mi * 16 + l15) * 32 + lg * 8);
#pragma unroll
    for (int ni = 0; ni < 4; ++ni)
      bfr[ni] = *(const s16x8*)(Bs + (ni * 16 + l15) * 32 + lg * 8);
#pragma unroll
    for (int mi = 0; mi < 2; ++mi)
#pragma unroll
      for (int ni = 0; ni < 4; ++ni)
        acc[mi][ni] = __builtin_amdgcn_mfma_f32_16x16x32_bf16(af[mi], bfr[ni], acc[mi][ni], 0, 0, 0);
    __syncthreads();
  }

#pragma unroll
  for (int mi = 0; mi < 2; ++mi)
#pragma unroll
    for (int ni = 0; ni < 4; ++ni)
#pragma unroll
      for (int r = 0; r < 4; ++r) {
        int row = brow + wave * 32 + mi * 16 + lg * 4 + r;
        int col = bcol + ni * 16 + l15;
        of[(size_t)row * N + col] = acc[mi][ni][r];
      }
}

// ---------------- fused causal shaped attention: 8-wave paired blocks ----------------
// grid (32=hb, 16=j), 512 threads. Waves 0-3: qt=j, waves 4-7: qt=31-j.
// No-max softmax (scores ~N(0,0.6) in log2 domain; exp2(-inf)=0 keeps causality).
// Row sum on the matrix pipe: acc_l += mfma(P, ones). Prefix-V via ones/masked
// MFMA every tile. NOTE: hb-fastest grid ordering already gives head->XCD
// affinity (bid%8 = hb%8), so KV panels are XCD-local by construction.
__global__ __launch_bounds__(512, 4) void attn_kernel(const bf16* __restrict__ qb,
                                                      const bf16* __restrict__ kb,
                                                      const bf16* __restrict__ vtb,
                                                      const float* __restrict__ rg,
                                                      const float* __restrict__ sg,
                                                      const float* __restrict__ cg,
                                                      bf16* __restrict__ out) {
  const int hb = blockIdx.x;            // h + 16*b
  const int h = hb & 15, b = hb >> 4;
  const int j = blockIdx.y;             // 0..15
  const int tid = threadIdx.x, wave = tid >> 6, lane = tid & 63;
  const int l15 = lane & 15, lg = lane >> 4;
  const int grp = wave >> 2, wv4 = wave & 3;
  const int qt = grp ? (31 - j) : j;    // this wave's q-tile
  const int ntm1 = 31 - j;              // last kv-tile index staged by the block

  __shared__ alignas(16) char Ks[2][64 * 128];  // K tile [kv][hd], swizzled, dbuf
  __shared__ alignas(16) char Vs[2][64 * 128];  // V^T tile [hd][kv], swizzled, dbuf
  __shared__ alignas(16) char Pl[8][2048];      // per-wave P [16 q][64 k], swizzled
  char* Plw = Pl[wave];
  const int swz = ((((l15 >> 3) ^ l15) & 7) << 4);

  const size_t hoff = ((size_t)b * NH + h) * NS * NHD;
  const bf16* K = kb + hoff;
  const bf16* VT = vtb + hoff;               // [HD=64][S=2048]
  const float rgh = rg[h], sgh = sg[h], cgh = cg[h];

  const int qbase = qt * 64 + wv4 * 16;
  const int qloc = wv4 * 16 + l15;           // q row within 64-tile for this lane

  // Q fragments (B-operand): Q[q=l15][hd]
  const bf16* Q = qb + hoff;
  s16x8 qa0 = *(const s16x8*)(Q + (size_t)(qbase + l15) * NHD + lg * 8);
  s16x8 qa1 = *(const s16x8*)(Q + (size_t)(qbase + l15) * NHD + 32 + lg * 8);

  // loop-invariant causal fragments for the prefix-sum MFMA (diag tile)
  const short ONE = 0x3F80;
  const s16x8 ones = {ONE, ONE, ONE, ONE, ONE, ONE, ONE, ONE};
  s16x8 pc0, pc1;
#pragma unroll
  for (int jj = 0; jj < 8; ++jj) {
    pc0[jj] = (lg * 8 + jj <= qloc) ? ONE : (short)0;
    pc1[jj] = (32 + lg * 8 + jj <= qloc) ? ONE : (short)0;
  }

  f32x4 acc_o[4] = {};
  f32x4 acc_c[4] = {};
  f32x4 acc_l = {};                    // row-sum of P (all cols identical)

  // staging: 512 threads, one 16B chunk of K and one of V per thread per tile
  const int srow = tid >> 3;           // 0..63
  const int sce = (tid & 7) * 8;       // element offset within row
  const int scb = (sce * 2) ^ SW(srow);

  // preload tile 0 into registers
  s16x8 kra = *(const s16x8*)(K + (size_t)srow * NHD + sce);
  s16x8 vra = *(const s16x8*)(VT + (size_t)srow * NS + sce);

  for (int t = 0; t <= ntm1; ++t) {
    char* Kb = Ks[t & 1];
    char* Vb = Vs[t & 1];
    // stage tile t (regs loaded last iter); other waves may still compute t-1
    *(s16x8*)(Kb + srow * 128 + scb) = kra;
    *(s16x8*)(Vb + srow * 128 + scb) = vra;
    if (t < ntm1) {                    // prefetch next tile (hides under compute)
      kra = *(const s16x8*)(K + ((size_t)(t + 1) * 64 + srow) * NHD + sce);
      vra = *(const s16x8*)(VT + (size_t)srow * NS + (t + 1) * 64 + sce);
    }
    __syncthreads();                   // tile t staged by all waves

    if (t > qt) continue;              // group done after its diag (barrier-only)
    const bool diag = (t == qt);

    // ---- swapped QK^T: sc[c] = S^T[k = c*16 + lg*4 + r][q = l15] ----
    f32x4 sc[4] = {};
    __builtin_amdgcn_s_setprio(1);
#pragma unroll
    for (int c = 0; c < 4; ++c) {
      const int R = c * 16 + l15;
      s16x8 kf0 = *(const s16x8*)(Kb + R * 128 + ((lg * 16) ^ SW(R)));
      s16x8 kf1 = *(const s16x8*)(Kb + R * 128 + ((64 + lg * 16) ^ SW(R)));
      sc[c] = __builtin_amdgcn_mfma_f32_16x16x32_bf16(kf0, qa0, sc[c], 0, 0, 0);
      sc[c] = __builtin_amdgcn_mfma_f32_16x16x32_bf16(kf1, qa1, sc[c], 0, 0, 0);
    }
    __builtin_amdgcn_s_setprio(0);

    // causal mask on the diagonal tile
    if (diag) {
#pragma unroll
      for (int c = 0; c < 4; ++c)
#pragma unroll
        for (int r = 0; r < 4; ++r)
          if (c * 16 + lg * 4 + r > qloc) sc[c][r] = -INFINITY;
    }

    // p = exp2(s) directly (no max subtraction); pack into A-frag layout:
    // row q=l15, k = c*16 + lg*4 + r
#pragma unroll
    for (int c = 0; c < 4; ++c) {
      s16x4 pk;
      pk[0] = (short)f2bu(exp2f(sc[c][0]));
      pk[1] = (short)f2bu(exp2f(sc[c][1]));
      pk[2] = (short)f2bu(exp2f(sc[c][2]));
      pk[3] = (short)f2bu(exp2f(sc[c][3]));
      *(s16x4*)(Plw + l15 * 128 + ((c * 32 + lg * 8) ^ swz)) = pk;
    }
    // read back as A-frags: P[q=l15][kv = khalf*32 + lg*8 + jj]
    s16x8 pa0 = *(const s16x8*)(Plw + l15 * 128 + ((lg * 16) ^ swz));
    s16x8 pa1 = *(const s16x8*)(Plw + l15 * 128 + ((64 + lg * 16) ^ swz));

    const s16x8 qc0 = diag ? pc0 : ones;
    const s16x8 qc1 = diag ? pc1 : ones;

    // ---- PV + prefix-V + row-sum, all on the matrix pipe ----
    __builtin_amdgcn_s_setprio(1);
    acc_l = __builtin_amdgcn_mfma_f32_16x16x32_bf16(pa0, ones, acc_l, 0, 0, 0);
    acc_l = __builtin_amdgcn_mfma_f32_16x16x32_bf16(pa1, ones, acc_l, 0, 0, 0);
#pragma unroll
    for (int sub = 0; sub < 4; ++sub) {
      const int Rv = sub * 16 + l15;
      s16x8 vf0 = *(const s16x8*)(Vb + Rv * 128 + ((lg * 16) ^ SW(Rv)));
      s16x8 vf1 = *(const s16x8*)(Vb + Rv * 128 + ((64 + lg * 16) ^ SW(Rv)));
      acc_o[sub] = __builtin_amdgcn_mfma_f32_16x16x32_bf16(pa0, vf0, acc_o[sub], 0, 0, 0);
      acc_o[sub] = __builtin_amdgcn_mfma_f32_16x16x32_bf16(pa1, vf1, acc_o[sub], 0, 0, 0);
      acc_c[sub] = __builtin_amdgcn_mfma_f32_16x16x32_bf16(qc0, vf0, acc_c[sub], 0, 0, 0);
      acc_c[sub] = __builtin_amdgcn_mfma_f32_16x16x32_bf16(qc1, vf1, acc_c[sub], 0, 0, 0);
    }
    __builtin_amdgcn_s_setprio(0);

    // ---- epilogue at this group's diagonal tile (V tile still resident) ----
    if (diag) {
      float linv[4];
#pragma unroll
      for (int r = 0; r < 4; ++r) linv[r] = 1.0f / acc_l[r];
#pragma unroll
      for (int sub = 0; sub < 4; ++sub) {
        const int d = sub * 16 + l15;
        const int cb = wv4 * 32 + lg * 8;  // byte col of local q rows (8B aligned)
        s16x4 vr4 = *(const s16x4*)(Vb + d * 128 + (cb ^ SW(d)));
        unsigned short vbits[4];
        __builtin_memcpy(vbits, &vr4, 8);
#pragma unroll
        for (int r = 0; r < 4; ++r) {
          int q = qbase + lg * 4 + r;
          float val = rgh * acc_o[sub][r] * linv[r] + sgh * b2f(vbits[r]) -
                      cgh * acc_c[sub][r] / (float)(q + 1);
          out[((size_t)b * NS + q) * ND + h * NHD + d] = __float2bfloat16(val);
        }
      }
    }
  }
}

extern "C" void kernel_launch(void* const* d_in, const int* in_sizes, int n_in,
                              void* d_out, int out_size, void* d_ws, size_t ws_size,
                              hipStream_t stream) {
  const float* x = (const float*)d_in[0];
  const float* qk_w = (const float*)d_in[1];
  const float* qk_b = (const float*)d_in[2];
  const float* v_w = (const float*)d_in[3];
  const float* cproj_w = (const float*)d_in[4];
  const float* rg = (const float*)d_in[5];
  const float* sg = (const float*)d_in[6];
  const float* cg = (const float*)d_in[7];
  float* out = (float*)d_out;

  char* p = (char*)d_ws;
  bf16* xb = (bf16*)p;   p += (size_t)4096 * 1024 * 2;   // x bf16 [B*S, D]
  bf16* qkwt = (bf16*)p; p += (size_t)2048 * 1024 * 2;   // qk_w^T bf16 [2D, D]
  bf16* vwt = (bf16*)p;  p += (size_t)1024 * 1024 * 2;   // v_w^T
  bf16* cpwt = (bf16*)p; p += (size_t)1024 * 1024 * 2;   // cproj_w^T
  bf16* qbuf = (bf16*)p; p += (size_t)NB * NH * NS * NHD * 2;
  bf16* kbuf = (bf16*)p; p += (size_t)NB * NH * NS * NHD * 2;
  bf16* vtbuf = (bf16*)p; p += (size_t)NB * NH * NS * NHD * 2;  // V^T [B,H,HD,S]
  bf16* aout = (bf16*)p; p += (size_t)4096 * 1024 * 2;   // attn out [B,S,D]

  prologue<<<dim3(64, 32, 4), dim3(32, 8), 0, stream>>>(x, qk_w, v_w, cproj_w,
                                                        xb, qkwt, vwt, cpwt);
  gemm_qkv<<<dim3(24, 32), 256, 0, stream>>>(xb, qkwt, vwt, qk_b, qbuf, kbuf, vtbuf);
  attn_kernel<<<dim3(32, 16), 512, 0, stream>>>(qbuf, kbuf, vtbuf, rg, sg, cg, aout);
  gemm_out<<<dim3(16, 32), 256, 0, stream>>>(aout, cpwt, out);
}